// Round 5
// baseline (229.191 us; speedup 1.0000x reference)
//
#include <hip/hip_runtime.h>

typedef _Float16 f16;
typedef _Float16 f16x4 __attribute__((ext_vector_type(4)));
typedef _Float16 f16x8 __attribute__((ext_vector_type(8)));
typedef float    f32x4 __attribute__((ext_vector_type(4)));

#define B_ 4
#define T_ 2048
#define C_ 1024
#define H_ 16
#define D_ 64

__device__ __forceinline__ void gload_lds16(const f16* g, f16* l) {
  __builtin_amdgcn_global_load_lds(
      (const __attribute__((address_space(1))) unsigned int*)g,
      (__attribute__((address_space(3))) unsigned int*)l, 16, 0, 0);
}

// ---------------- prep kernels ----------------
__global__ void cvt_kernel(const float* __restrict__ in, f16* __restrict__ out, int n4) {
  int i = blockIdx.x * blockDim.x + threadIdx.x;
  int stride = gridDim.x * blockDim.x;
  for (; i < n4; i += stride) {
    float4 v = ((const float4*)in)[i];
    f16x4 h = { (f16)v.x, (f16)v.y, (f16)v.z, (f16)v.w };
    ((f16x4*)out)[i] = h;
  }
}

__global__ void transpose_cvt_kernel(const float* __restrict__ W, f16* __restrict__ Wt,
                                     int K, int N) {
  __shared__ f16 tile[32][33];
  int bx = blockIdx.x, by = blockIdx.y;
  int tx = threadIdx.x & 31, ty = threadIdx.x >> 5;
  #pragma unroll
  for (int i = ty; i < 32; i += 8)
    tile[i][tx] = (f16)W[(size_t)(by * 32 + i) * N + bx * 32 + tx];
  __syncthreads();
  #pragma unroll
  for (int i = ty; i < 32; i += 8)
    Wt[(size_t)(bx * 32 + i) * K + by * 32 + tx] = tile[tx][i];
}

// ============ 256x256 8-phase QKV GEMM (m201 template, f16) ============
// A[M,K] * Bt[N,K]^T + bias -> scatter to Q/K/Vt. M=8192, N=3072, K=1024.
// 8 waves (2M x 4N), BK=64, dbuf x 2-half LDS (128KB), st_16x32 swizzle,
// counted vmcnt(2) gates at phases 4/8 only, setprio around MFMA clusters.
__global__ __launch_bounds__(512, 2)
void gemm256_kernel(const f16* __restrict__ A, const f16* __restrict__ Bt,
                    const float* __restrict__ bias,
                    f16* __restrict__ q, f16* __restrict__ kk, f16* __restrict__ vt) {
  const int M_ = 8192, N_ = 3072, K_ = 1024;
  __shared__ __align__(16) f16 As[2][2][128 * 64];  // [buf][half][row*64+col]
  __shared__ __align__(16) f16 Bs[2][2][128 * 64];

  const int bid = blockIdx.x;
  const int wg = (bid & 7) * 48 + (bid >> 3);   // bijective XCD swizzle (384%8==0)
  const int bm = wg / 12, bn = wg % 12;
  const int m0 = bm << 8, n0 = bn << 8;
  const int lane = threadIdx.x & 63, wid = threadIdx.x >> 6;
  const int wm = wid >> 2;            // A half (rows wm*128..+127)
  const int bhalf = (wid >> 1) & 1;   // B half
  const int brow0 = (wid & 1) << 6;   // row-in-half base for B frags
  const int rr = lane & 15, g = lane >> 4;
  const int swz = (rr & 4) << 3;      // st_16x32: XOR byte-bit-5 with row-bit-2

  f32x4 acc[8][4] = {};

  // ---- staging geometry (linear LDS dest, pre-swizzled global source) ----
  // lane l writes dest bytes  w*1024 + l*16  (+ c*8192)  ->
  // row = c*64 + w*8 + (l>>3), src colbyte = ((l&7)<<4) ^ (l&32)
  const int srow = (wid << 3) + (lane >> 3);
  const int scol = ((((lane & 7) << 4) ^ (lane & 32)) >> 1);  // f16 units
  const f16* Abase = A + (size_t)(m0 + srow) * K_ + scol;
  const f16* Bbase = Bt + (size_t)(n0 + srow) * K_ + scol;

  auto STAGE_A = [&](int buf, int half, int tile) {
    #pragma unroll
    for (int c = 0; c < 2; ++c)
      gload_lds16(Abase + (size_t)(half * 128 + c * 64) * K_ + tile * 64,
                  &As[buf][half][c * 4096 + wid * 512]);
  };
  auto STAGE_B = [&](int buf, int half, int tile) {
    #pragma unroll
    for (int c = 0; c < 2; ++c)
      gload_lds16(Bbase + (size_t)(half * 128 + c * 64) * K_ + tile * 64,
                  &Bs[buf][half][c * 4096 + wid * 512]);
  };

  auto LDA = [&](int buf, int mhalf, int kkk, f16x8* af) {
    #pragma unroll
    for (int f = 0; f < 4; ++f)
      af[f] = *(const f16x8*)((const char*)&As[buf][wm][0]
               + (mhalf * 64 + f * 16 + rr) * 128 + ((kkk * 64 + g * 16) ^ swz));
  };
  auto LDB = [&](int buf, int kkk, f16x8* bf) {
    #pragma unroll
    for (int nf = 0; nf < 4; ++nf)
      bf[nf] = *(const f16x8*)((const char*)&Bs[buf][bhalf][0]
               + (brow0 + nf * 16 + rr) * 128 + ((kkk * 64 + g * 16) ^ swz));
  };

  #define BAR() { __builtin_amdgcn_s_barrier(); __builtin_amdgcn_sched_barrier(0); }
  #define MMA(MH, AF, BF) { \
    __builtin_amdgcn_s_setprio(1); \
    _Pragma("unroll") \
    for (int f = 0; f < 4; ++f) \
      _Pragma("unroll") \
      for (int nf = 0; nf < 4; ++nf) \
        acc[(MH) * 4 + f][nf] = \
            __builtin_amdgcn_mfma_f32_16x16x32_f16(AF[f], BF[nf], acc[(MH) * 4 + f][nf], 0, 0, 0); \
    __builtin_amdgcn_s_setprio(0); }

  // ---- prologue: tile0 (buf0) fully + tile1 B.h0 (buf1) ----
  STAGE_A(0, 0, 0); STAGE_A(0, 1, 0);
  STAGE_B(0, 0, 0); STAGE_B(0, 1, 0);
  STAGE_B(1, 0, 1);
  asm volatile("s_waitcnt vmcnt(2)" ::: "memory");
  BAR();

  const int NT = 16;  // K tiles
  #pragma unroll 1
  for (int i = 0; i < 8; ++i) {
    const int t1 = 2 * i + 1, t2 = 2 * i + 2, t3 = 2 * i + 3;
    f16x8 af[4], bf[4];
    // ph1: buf0 (mh0,kk0); stage B1h1(t1)
    LDB(0, 0, bf); LDA(0, 0, 0, af);
    STAGE_B(1, 1, t1);
    BAR(); MMA(0, af, bf); BAR();
    // ph2: buf0 (mh1,kk0); stage A1h0(t1)
    LDA(0, 1, 0, af);
    STAGE_A(1, 0, t1);
    BAR(); MMA(1, af, bf); BAR();
    // ph3: buf0 (mh0,kk1); stage A1h1(t1)
    LDB(0, 1, bf); LDA(0, 0, 1, af);
    STAGE_A(1, 1, t1);
    BAR(); MMA(0, af, bf); BAR();
    // ph4: buf0 (mh1,kk1); stage B0h0(t2); GATE
    LDA(0, 1, 1, af);
    if (t2 < NT) {
      STAGE_B(0, 0, t2);
      asm volatile("s_waitcnt vmcnt(2)" ::: "memory");
    } else {
      asm volatile("s_waitcnt vmcnt(0)" ::: "memory");
    }
    BAR(); MMA(1, af, bf); BAR();
    // ph5: buf1 (mh0,kk0); stage B0h1(t2)
    LDB(1, 0, bf); LDA(1, 0, 0, af);
    if (t2 < NT) STAGE_B(0, 1, t2);
    BAR(); MMA(0, af, bf); BAR();
    // ph6: buf1 (mh1,kk0); stage A0h0(t2)
    LDA(1, 1, 0, af);
    if (t2 < NT) STAGE_A(0, 0, t2);
    BAR(); MMA(1, af, bf); BAR();
    // ph7: buf1 (mh0,kk1); stage A0h1(t2)
    LDB(1, 1, bf); LDA(1, 0, 1, af);
    if (t2 < NT) STAGE_A(0, 1, t2);
    BAR(); MMA(0, af, bf); BAR();
    // ph8: buf1 (mh1,kk1); stage B1h0(t3); GATE
    LDA(1, 1, 1, af);
    if (t3 < NT) {
      STAGE_B(1, 0, t3);
      asm volatile("s_waitcnt vmcnt(2)" ::: "memory");
    } else if (i < 7) {
      asm volatile("s_waitcnt vmcnt(0)" ::: "memory");
    }
    BAR(); MMA(1, af, bf); BAR();
  }
  #undef MMA
  #undef BAR

  // ---- epilogue: scatter to q/k/vt (block-uniform segment) ----
  const int col = lane & 15;
  const int row4 = (lane >> 4) << 2;
  const int seg = n0 >> 10;          // 0=q 1=k 2=v, uniform per block
  #pragma unroll
  for (int mi = 0; mi < 8; ++mi) {
    #pragma unroll
    for (int nf = 0; nf < 4; ++nf) {
      const int n = n0 + (wid & 3) * 64 + nf * 16 + col;
      const float bn_ = bias[n];
      const int cc = n & 1023;
      const int h = cc >> 6, d = cc & 63;
      #pragma unroll
      for (int r = 0; r < 4; ++r) {
        const int m = m0 + wm * 128 + mi * 16 + row4 + r;
        const float v = acc[mi][nf][r] + bn_;
        const int b = m >> 11, t = m & 2047;
        const size_t bh = (size_t)b * 16 + h;
        const f16 hv = (f16)v;
        if (seg == 0)      q [(bh * T_ + t) * D_ + d] = hv;
        else if (seg == 1) kk[(bh * T_ + t) * D_ + d] = hv;
        else               vt[(bh * D_ + d) * T_ + t] = hv;
      }
    }
  }
}

// ---------------- 128^2 GEMM (out-proj): C = A*Bt^T + bias, fp32 out --------
__global__ __launch_bounds__(256, 3)
void gemm_kernel(const f16* __restrict__ A, const f16* __restrict__ Bt,
                 const float* __restrict__ bias, float* __restrict__ outF,
                 int M, int N, int K) {
  __shared__ __align__(16) f16 As[3][128 * 32];
  __shared__ __align__(16) f16 Bs[3][128 * 32];
  const int nbn = N >> 7;
  const int bid = blockIdx.x;
  const int bm = bid / nbn, bn = bid % nbn;
  const int m0 = bm << 7, n0 = bn << 7;
  const int tid = threadIdx.x;
  const int lane = tid & 63, wid = tid >> 6;
  const int wr = wid >> 1, wc = wid & 1;

  f32x4 acc[4][4] = {};

  const int srow = lane >> 2;
  const int scol = (lane & 3) << 3;
  const f16* Abase = A + (size_t)(m0 + srow) * K + scol;
  const f16* Bbase = Bt + (size_t)(n0 + srow) * K + scol;

  auto stage = [&](int buf, int kt) {
    const int c0 = wid * 2;
    #pragma unroll
    for (int c = c0; c < c0 + 2; ++c) {
      gload_lds16(Abase + (size_t)c * 16 * K + kt * 32, &As[buf][c * 512]);
      gload_lds16(Bbase + (size_t)c * 16 * K + kt * 32, &Bs[buf][c * 512]);
    }
  };

  const int ko = (lane >> 4) << 3;
  const int rr = lane & 15;

  auto compute = [&](int buf) {
    f16x8 af[4], bf[4];
    #pragma unroll
    for (int t = 0; t < 4; ++t) {
      af[t] = *(const f16x8*)&As[buf][(wr * 64 + t * 16 + rr) * 32 + ko];
      bf[t] = *(const f16x8*)&Bs[buf][(wc * 64 + t * 16 + rr) * 32 + ko];
    }
    __builtin_amdgcn_s_setprio(1);
    #pragma unroll
    for (int i = 0; i < 4; ++i)
      #pragma unroll
      for (int j = 0; j < 4; ++j)
        acc[i][j] = __builtin_amdgcn_mfma_f32_16x16x32_f16(af[i], bf[j], acc[i][j], 0, 0, 0);
    __builtin_amdgcn_s_setprio(0);
  };

  const int nk = K >> 5;
  int bcur = 0, bnext = 1, bnn = 2;
  stage(0, 0);
  stage(1, 1);
  asm volatile("s_waitcnt vmcnt(4)" ::: "memory");
  __builtin_amdgcn_s_barrier();
  __builtin_amdgcn_sched_barrier(0);
  for (int t = 0; t < nk; ++t) {
    if (t + 2 < nk) stage(bnn, t + 2);
    compute(bcur);
    if (t + 1 < nk) {
      if (t + 2 < nk) asm volatile("s_waitcnt vmcnt(4)" ::: "memory");
      else            asm volatile("s_waitcnt vmcnt(0)" ::: "memory");
      __builtin_amdgcn_s_barrier();
      __builtin_amdgcn_sched_barrier(0);
    }
    const int tmp = bcur; bcur = bnext; bnext = bnn; bnn = tmp;
  }

  const int col = lane & 15;
  const int row4 = (lane >> 4) << 2;
  #pragma unroll
  for (int i = 0; i < 4; ++i) {
    #pragma unroll
    for (int j = 0; j < 4; ++j) {
      const int n = n0 + wc * 64 + j * 16 + col;
      const float bn_ = bias[n];
      #pragma unroll
      for (int r = 0; r < 4; ++r) {
        const int m = m0 + wr * 64 + i * 16 + row4 + r;
        outF[(size_t)m * N + n] = acc[i][j][r] + bn_;
      }
    }
  }
}

// ---------------- causal flash attention (unchanged) ----------------
__global__ __launch_bounds__(512, 2)
void attn_kernel(const f16* __restrict__ Q, const f16* __restrict__ Kg,
                 const f16* __restrict__ Vt, f16* __restrict__ Aout) {
  __shared__ __align__(16) f16 Ks[2][64 * 64];
  __shared__ __align__(16) f16 Vs[2][64 * 64];
  __shared__ __align__(16) f16 Pt[8][16][72];

  const int bid = blockIdx.x;
  const int wgid = (bid & 7) * 128 + (bid >> 3);
  const int bh = wgid >> 4;
  const int ti = 15 - (wgid & 15);
  const int lane = threadIdx.x & 63, w = threadIdx.x >> 6;
  const int col = lane & 15;
  const int g = lane >> 4;
  const int ko = g << 3;

  const f16* Qp = Q + (size_t)bh * T_ * D_;
  const f16* Kp = Kg + (size_t)bh * T_ * D_;
  const f16* Vp = Vt + (size_t)bh * D_ * T_;

  const int srow8 = lane >> 3;
  const int scb = ((lane & 7) << 4) ^ (srow8 << 4);
  const int krow_s = (w << 3) + srow8;

  auto stage = [&](int buf, int kb) {
    gload_lds16(Kp + (size_t)(kb + krow_s) * D_ + (scb >> 1), &Ks[buf][w * 512]);
    gload_lds16(Vp + (size_t)krow_s * T_ + kb + (scb >> 1), &Vs[buf][w * 512]);
  };
  auto ldsK = [&](int buf, int krow, int d0) -> f16x8 {
    const int off = krow * 128 + ((d0 << 1) ^ ((krow & 7) << 4));
    return *(const f16x8*)((const char*)&Ks[buf][0] + off);
  };
  auto ldsV = [&](int buf, int drow, int k0) -> f16x8 {
    const int off = drow * 128 + ((k0 << 1) ^ ((drow & 7) << 4));
    return *(const f16x8*)((const char*)&Vs[buf][0] + off);
  };

  const int q0 = ti << 7;
  const int qrow0 = q0 + (w << 4);
  const int nkt = (ti << 1) + 2;
  const int qg = qrow0 + col;

  f16x8 qf[2];
  #pragma unroll
  for (int s = 0; s < 2; ++s) {
    f16x8 t = *(const f16x8*)&Qp[(size_t)qg * D_ + s * 32 + ko];
    #pragma unroll
    for (int e = 0; e < 8; ++e) t[e] = t[e] * (f16)0.125f;
    qf[s] = t;
  }

  f32x4 o[4] = {};
  float m = -1e30f, l = 0.f;

  stage(0, 0);
  __syncthreads();
  int cur = 0;
  for (int kt = 0; kt < nkt; ++kt) {
    const int kb = kt << 6;
    if (kt + 1 < nkt) stage(cur ^ 1, (kt + 1) << 6);

    if (kb <= qrow0 + 15) {
      f32x4 sc[4] = {};
      #pragma unroll
      for (int s = 0; s < 2; ++s)
        #pragma unroll
        for (int mt = 0; mt < 4; ++mt) {
          f16x8 kf = ldsK(cur, mt * 16 + col, s * 32 + ko);
          sc[mt] = __builtin_amdgcn_mfma_f32_16x16x32_f16(kf, qf[s], sc[mt], 0, 0, 0);
        }

      const bool needMask = (kb + 63 > qrow0);
      if (needMask) {
        #pragma unroll
        for (int mt = 0; mt < 4; ++mt)
          #pragma unroll
          for (int r = 0; r < 4; ++r)
            if (kb + mt * 16 + (g << 2) + r > qg) sc[mt][r] = -1e30f;
      }

      float mx = fmaxf(fmaxf(fmaxf(sc[0][0], sc[0][1]), fmaxf(sc[0][2], sc[0][3])),
                       fmaxf(fmaxf(sc[1][0], sc[1][1]), fmaxf(sc[1][2], sc[1][3])));
      mx = fmaxf(mx, fmaxf(fmaxf(fmaxf(sc[2][0], sc[2][1]), fmaxf(sc[2][2], sc[2][3])),
                           fmaxf(fmaxf(sc[3][0], sc[3][1]), fmaxf(sc[3][2], sc[3][3]))));
      mx = fmaxf(mx, __shfl_xor(mx, 16, 64));
      mx = fmaxf(mx, __shfl_xor(mx, 32, 64));

      if (!__all(mx - m <= 8.f)) {
        const float mnew = fmaxf(m, mx);
        const float alpha = __expf(m - mnew);
        m = mnew;
        l *= alpha;
        #pragma unroll
        for (int mt = 0; mt < 4; ++mt)
          #pragma unroll
          for (int r = 0; r < 4; ++r) o[mt][r] *= alpha;
      }

      float rs = 0.f;
      #pragma unroll
      for (int mt = 0; mt < 4; ++mt) {
        f16x4 ph;
        #pragma unroll
        for (int r = 0; r < 4; ++r) {
          const float p = __expf(sc[mt][r] - m);
          rs += p;
          ph[r] = (f16)p;
        }
        *(f16x4*)&Pt[w][col][mt * 16 + (g << 2)] = ph;
      }
      rs += __shfl_xor(rs, 16, 64);
      rs += __shfl_xor(rs, 32, 64);
      l += rs;

      #pragma unroll
      for (int s = 0; s < 2; ++s) {
        f16x8 pb = *(const f16x8*)&Pt[w][col][s * 32 + ko];
        #pragma unroll
        for (int mt = 0; mt < 4; ++mt) {
          f16x8 vf = ldsV(cur, mt * 16 + col, s * 32 + ko);
          o[mt] = __builtin_amdgcn_mfma_f32_16x16x32_f16(vf, pb, o[mt], 0, 0, 0);
        }
      }
    }

    __syncthreads();
    cur ^= 1;
  }

  const int b = bh >> 4, h = bh & 15;
  const float inv = 1.0f / l;
  const size_t rowoff = ((size_t)b * T_ + qg) * C_ + (size_t)h * D_;
  #pragma unroll
  for (int mt = 0; mt < 4; ++mt) {
    f16x4 ov;
    #pragma unroll
    for (int r = 0; r < 4; ++r) ov[r] = (f16)(o[mt][r] * inv);
    *(f16x4*)&Aout[rowoff + mt * 16 + (g << 2)] = ov;
  }
}

// ---------------- launch ----------------
extern "C" void kernel_launch(void* const* d_in, const int* in_sizes, int n_in,
                              void* d_out, int out_size, void* d_ws, size_t ws_size,
                              hipStream_t stream) {
  const float* x    = (const float*)d_in[0];
  const float* Wqkv = (const float*)d_in[1];
  const float* bqkv = (const float*)d_in[2];
  const float* Wout = (const float*)d_in[3];
  const float* bout = (const float*)d_in[4];
  float* out = (float*)d_out;

  char* ws = (char*)d_ws;
  f16* xb     = (f16*)ws;                   // 16MB (x in f16; later reused as Aout)
  f16* Wqkv_t = (f16*)(ws + (16u << 20));   // 6MB  [3072,1024]
  f16* Wout_t = (f16*)(ws + (22u << 20));   // 2MB  [1024,1024]
  f16* Qb     = (f16*)(ws + (24u << 20));   // 16MB [B,H,T,D]
  f16* Kb     = (f16*)(ws + (40u << 20));   // 16MB [B,H,T,D]
  f16* Vtb    = (f16*)(ws + (56u << 20));   // 16MB [B,H,D,T]

  cvt_kernel<<<2048, 256, 0, stream>>>(x, xb, (B_ * T_ * C_) / 4);
  dim3 g1(3072 / 32, 1024 / 32);
  transpose_cvt_kernel<<<g1, 256, 0, stream>>>(Wqkv, Wqkv_t, 1024, 3072);
  dim3 g2(1024 / 32, 1024 / 32);
  transpose_cvt_kernel<<<g2, 256, 0, stream>>>(Wout, Wout_t, 1024, 1024);

  gemm256_kernel<<<384, 512, 0, stream>>>(xb, Wqkv_t, bqkv, Qb, Kb, Vtb);
  attn_kernel<<<1024, 512, 0, stream>>>(Qb, Kb, Vtb, xb /*Aout alias*/);
  gemm_kernel<<<64 * 8, 256, 0, stream>>>(xb, Wout_t, bout, out, 8192, 1024, 1024);
}

// Round 6
// 213.050 us; speedup vs baseline: 1.0758x; 1.0758x over previous
//
#include <hip/hip_runtime.h>

typedef _Float16 f16;
typedef _Float16 f16x4 __attribute__((ext_vector_type(4)));
typedef _Float16 f16x8 __attribute__((ext_vector_type(8)));
typedef float    f32x4 __attribute__((ext_vector_type(4)));

#define B_ 4
#define T_ 2048
#define C_ 1024
#define H_ 16
#define D_ 64

__device__ __forceinline__ void gload_lds16(const f16* g, f16* l) {
  __builtin_amdgcn_global_load_lds(
      (const __attribute__((address_space(1))) unsigned int*)g,
      (__attribute__((address_space(3))) unsigned int*)l, 16, 0, 0);
}

// ---------------- prep kernels ----------------
__global__ void cvt_kernel(const float* __restrict__ in, f16* __restrict__ out, int n4) {
  int i = blockIdx.x * blockDim.x + threadIdx.x;
  int stride = gridDim.x * blockDim.x;
  for (; i < n4; i += stride) {
    float4 v = ((const float4*)in)[i];
    f16x4 h = { (f16)v.x, (f16)v.y, (f16)v.z, (f16)v.w };
    ((f16x4*)out)[i] = h;
  }
}

__global__ void transpose_cvt_kernel(const float* __restrict__ W, f16* __restrict__ Wt,
                                     int K, int N) {
  __shared__ f16 tile[32][33];
  int bx = blockIdx.x, by = blockIdx.y;
  int tx = threadIdx.x & 31, ty = threadIdx.x >> 5;
  #pragma unroll
  for (int i = ty; i < 32; i += 8)
    tile[i][tx] = (f16)W[(size_t)(by * 32 + i) * N + bx * 32 + tx];
  __syncthreads();
  #pragma unroll
  for (int i = ty; i < 32; i += 8)
    Wt[(size_t)(bx * 32 + i) * K + by * 32 + tx] = tile[tx][i];
}

// ---------------- GEMM: C = A[M,K] * Bt[N,K]^T + bias (R4 version, measured 99us) ----
template <int EPI>
__global__ __launch_bounds__(256, 3)
void gemm_kernel(const f16* __restrict__ A, const f16* __restrict__ Bt,
                 const float* __restrict__ bias, float* __restrict__ outF,
                 f16* __restrict__ q, f16* __restrict__ kk, f16* __restrict__ vt,
                 int M, int N, int K) {
  __shared__ __align__(16) f16 As[3][128 * 32];
  __shared__ __align__(16) f16 Bs[3][128 * 32];
  const int nbn = N >> 7;
  const int bid = blockIdx.x;
  const int bm = bid / nbn, bn = bid % nbn;
  const int m0 = bm << 7, n0 = bn << 7;
  const int tid = threadIdx.x;
  const int lane = tid & 63, wid = tid >> 6;
  const int wr = wid >> 1, wc = wid & 1;

  f32x4 acc[4][4] = {};

  const int srow = lane >> 2;
  const int scol = (((lane & 3) ^ ((lane >> 2) & 3)) << 3);
  const f16* Abase = A + (size_t)(m0 + srow) * K + scol;
  const f16* Bbase = Bt + (size_t)(n0 + srow) * K + scol;

  auto stage = [&](int buf, int kt) {
    const int c0 = wid * 2;
    #pragma unroll
    for (int c = c0; c < c0 + 2; ++c) {
      gload_lds16(Abase + (size_t)c * 16 * K + kt * 32, &As[buf][c * 512]);
      gload_lds16(Bbase + (size_t)c * 16 * K + kt * 32, &Bs[buf][c * 512]);
    }
  };

  const int g = lane >> 4;
  const int rr = lane & 15;
  const int swz = (g ^ (rr & 3)) << 4;

  auto compute = [&](int buf) {
    f16x8 af[4], bf[4];
    #pragma unroll
    for (int t = 0; t < 4; ++t) {
      af[t] = *(const f16x8*)((const char*)&As[buf][0] + (wr * 64 + t * 16 + rr) * 64 + swz);
      bf[t] = *(const f16x8*)((const char*)&Bs[buf][0] + (wc * 64 + t * 16 + rr) * 64 + swz);
    }
    __builtin_amdgcn_s_setprio(1);
    #pragma unroll
    for (int i = 0; i < 4; ++i)
      #pragma unroll
      for (int j = 0; j < 4; ++j)
        acc[i][j] = __builtin_amdgcn_mfma_f32_16x16x32_f16(af[i], bf[j], acc[i][j], 0, 0, 0);
    __builtin_amdgcn_s_setprio(0);
  };

  const int nk = K >> 5;
  int bcur = 0, bnext = 1, bnn = 2;
  stage(0, 0);
  stage(1, 1);
  asm volatile("s_waitcnt vmcnt(4)" ::: "memory");
  __builtin_amdgcn_s_barrier();
  __builtin_amdgcn_sched_barrier(0);
  for (int t = 0; t < nk; ++t) {
    if (t + 2 < nk) stage(bnn, t + 2);
    compute(bcur);
    if (t + 1 < nk) {
      if (t + 2 < nk) asm volatile("s_waitcnt vmcnt(4)" ::: "memory");
      else            asm volatile("s_waitcnt vmcnt(0)" ::: "memory");
      __builtin_amdgcn_s_barrier();
      __builtin_amdgcn_sched_barrier(0);
    }
    const int tmp = bcur; bcur = bnext; bnext = bnn; bnn = tmp;
  }

  const int col = lane & 15;
  const int row4 = (lane >> 4) << 2;
  #pragma unroll
  for (int i = 0; i < 4; ++i) {
    #pragma unroll
    for (int j = 0; j < 4; ++j) {
      const int n = n0 + wc * 64 + j * 16 + col;
      const float bn_ = bias[n];
      #pragma unroll
      for (int r = 0; r < 4; ++r) {
        const int m = m0 + wr * 64 + i * 16 + row4 + r;
        const float v = acc[i][j][r] + bn_;
        if (EPI == 1) {
          outF[(size_t)m * N + n] = v;
        } else {
          const int which = n >> 10;           // 0=q 1=k 2=v
          const int cc = n & 1023;
          const int h = cc >> 6, d = cc & 63;
          const int b = m >> 11, t = m & 2047;
          const size_t bh = (size_t)b * 16 + h;
          const f16 hv = (f16)v;
          if (which == 0)      q [(bh * T_ + t) * D_ + d] = hv;
          else if (which == 1) kk[(bh * T_ + t) * D_ + d] = hv;
          else                 vt[(bh * D_ + d) * T_ + t] = hv;  // V transposed
        }
      }
    }
  }
}

// ---------------- causal flash attention ----------------
// 256 blocks (1/CU): xcd = bid&7, bh = 8*xcd..8*xcd+7 (K/V fits XCD L2),
// pair in [0,4): block handles q-tiles (pair, 7-pair) of 256 rows -> uniform
// 36 kt. Block = 8 waves x 32 q-rows (2 fragments/wave share K/V reads).
// K/V: TRIPLE-buffered LDS, 2-deep prefetch, counted vmcnt(2) + raw s_barrier.
__global__ __launch_bounds__(512, 1)
void attn_kernel(const f16* __restrict__ Q, const f16* __restrict__ Kg,
                 const f16* __restrict__ Vt, f16* __restrict__ Aout) {
  __shared__ __align__(16) f16 Ks[3][64 * 64];   // [kvrow][d], rows 128B, swizzled
  __shared__ __align__(16) f16 Vs[3][64 * 64];   // [d][kv],   rows 128B, swizzled
  __shared__ __align__(16) f16 Pt[8][32][72];    // per-wave P^T [q(32)][kv], +8 pad

  const int bid = blockIdx.x;
  const int wgid = (bid & 7) * 32 + (bid >> 3);  // bijective, 32 blocks/XCD
  const int bh = wgid >> 2;
  const int pair = wgid & 3;
  const int lane = threadIdx.x & 63, w = threadIdx.x >> 6;
  const int col = lane & 15;
  const int g = lane >> 4;
  const int ko = g << 3;

  const f16* Qp = Q + (size_t)bh * T_ * D_;
  const f16* Kp = Kg + (size_t)bh * T_ * D_;
  const f16* Vp = Vt + (size_t)bh * D_ * T_;

  // staging: wave w stages 1KB chunk w of K and of V (linear LDS dest,
  // pre-swizzled global source; rule #21)
  const int srow8 = lane >> 3;
  const int scb = ((lane & 7) << 4) ^ (srow8 << 4);
  const int krow_s = (w << 3) + srow8;

  auto stage = [&](int buf, int kb) {
    gload_lds16(Kp + (size_t)(kb + krow_s) * D_ + (scb >> 1), &Ks[buf][w * 512]);
    gload_lds16(Vp + (size_t)krow_s * T_ + kb + (scb >> 1), &Vs[buf][w * 512]);
  };
  auto ldsK = [&](int buf, int krow, int d0) -> f16x8 {
    const int off = krow * 128 + ((d0 << 1) ^ ((krow & 7) << 4));
    return *(const f16x8*)((const char*)&Ks[buf][0] + off);
  };
  auto ldsV = [&](int buf, int drow, int k0) -> f16x8 {
    const int off = drow * 128 + ((k0 << 1) ^ ((drow & 7) << 4));
    return *(const f16x8*)((const char*)&Vs[buf][0] + off);
  };

  const int b = bh >> 4, hd = bh & 15;

  #pragma unroll 1
  for (int tt = 0; tt < 2; ++tt) {
    const int ti = tt ? (7 - pair) : pair;
    const int q0 = ti << 8;
    const int qrow0 = q0 + (w << 5);           // wave owns 32 q-rows
    const int nkt = (ti + 1) << 2;

    // Q fragments (B-operand), pre-scaled by 1/sqrt(D)
    f16x8 qf[2][2];
    #pragma unroll
    for (int h = 0; h < 2; ++h)
      #pragma unroll
      for (int s = 0; s < 2; ++s) {
        f16x8 t = *(const f16x8*)&Qp[(size_t)(qrow0 + h * 16 + col) * D_ + s * 32 + ko];
        #pragma unroll
        for (int e = 0; e < 8; ++e) t[e] = t[e] * (f16)0.125f;
        qf[h][s] = t;
      }

    f32x4 o[2][4] = {};
    float m[2] = {-1e30f, -1e30f}, l[2] = {0.f, 0.f};

    int b0 = 0, b1 = 1, b2 = 2;
    stage(b0, 0);
    stage(b1, 64);
    asm volatile("s_waitcnt vmcnt(2)" ::: "memory");
    __builtin_amdgcn_s_barrier();
    __builtin_amdgcn_sched_barrier(0);

    for (int kt = 0; kt < nkt; ++kt) {
      const int kb = kt << 6;
      if (kt + 2 < nkt) stage(b2, kb + 128);

      if (kb <= qrow0 + 31) {  // wave has unmasked work
        // QK^T (swapped): sc[h][mt][r] = S[kv=kb+mt*16+g*4+r][q=qrow0+h*16+col]
        f32x4 sc[2][4] = {};
        #pragma unroll
        for (int s = 0; s < 2; ++s)
          #pragma unroll
          for (int mt = 0; mt < 4; ++mt) {
            f16x8 kf = ldsK(b0, mt * 16 + col, s * 32 + ko);
            sc[0][mt] = __builtin_amdgcn_mfma_f32_16x16x32_f16(kf, qf[0][s], sc[0][mt], 0, 0, 0);
            sc[1][mt] = __builtin_amdgcn_mfma_f32_16x16x32_f16(kf, qf[1][s], sc[1][mt], 0, 0, 0);
          }

        if (kb + 63 > qrow0) {  // causal mask (diagonal region only)
          #pragma unroll
          for (int mt = 0; mt < 4; ++mt)
            #pragma unroll
            for (int r = 0; r < 4; ++r) {
              const int kv = kb + mt * 16 + (g << 2) + r;
              if (kv > qrow0 + col)      sc[0][mt][r] = -1e30f;
              if (kv > qrow0 + 16 + col) sc[1][mt][r] = -1e30f;
            }
        }

        // row max: in-lane over 16 + 2 shfl_xor
        float mx[2];
        #pragma unroll
        for (int h = 0; h < 2; ++h) {
          float v = fmaxf(fmaxf(fmaxf(sc[h][0][0], sc[h][0][1]), fmaxf(sc[h][0][2], sc[h][0][3])),
                          fmaxf(fmaxf(sc[h][1][0], sc[h][1][1]), fmaxf(sc[h][1][2], sc[h][1][3])));
          v = fmaxf(v, fmaxf(fmaxf(fmaxf(sc[h][2][0], sc[h][2][1]), fmaxf(sc[h][2][2], sc[h][2][3])),
                             fmaxf(fmaxf(sc[h][3][0], sc[h][3][1]), fmaxf(sc[h][3][2], sc[h][3][3]))));
          v = fmaxf(v, __shfl_xor(v, 16, 64));
          v = fmaxf(v, __shfl_xor(v, 32, 64));
          mx[h] = v;
        }

        // defer-rescale (T13)
        if (!__all(fmaxf(mx[0] - m[0], mx[1] - m[1]) <= 8.f)) {
          #pragma unroll
          for (int h = 0; h < 2; ++h) {
            const float mnew = fmaxf(m[h], mx[h]);
            const float alpha = __expf(m[h] - mnew);
            m[h] = mnew;
            l[h] *= alpha;
            #pragma unroll
            for (int mt = 0; mt < 4; ++mt)
              #pragma unroll
              for (int r = 0; r < 4; ++r) o[h][mt][r] *= alpha;
          }
        }

        // P = exp(S - m), store P^T[q][kv] (b64 writes), row-sum via 2 shfl
        #pragma unroll
        for (int h = 0; h < 2; ++h) {
          float rs = 0.f;
          #pragma unroll
          for (int mt = 0; mt < 4; ++mt) {
            f16x4 ph;
            #pragma unroll
            for (int r = 0; r < 4; ++r) {
              const float p = __expf(sc[h][mt][r] - m[h]);
              rs += p;
              ph[r] = (f16)p;
            }
            *(f16x4*)&Pt[w][h * 16 + col][mt * 16 + (g << 2)] = ph;
          }
          rs += __shfl_xor(rs, 16, 64);
          rs += __shfl_xor(rs, 32, 64);
          l[h] += rs;
        }

        // PV (swapped): o[h][mt][r] = O[q][d=mt*16+g*4+r]; V frag shared by both h
        #pragma unroll
        for (int s = 0; s < 2; ++s) {
          f16x8 pb0 = *(const f16x8*)&Pt[w][col][s * 32 + ko];
          f16x8 pb1 = *(const f16x8*)&Pt[w][16 + col][s * 32 + ko];
          #pragma unroll
          for (int mt = 0; mt < 4; ++mt) {
            f16x8 vf = ldsV(b0, mt * 16 + col, s * 32 + ko);
            o[0][mt] = __builtin_amdgcn_mfma_f32_16x16x32_f16(vf, pb0, o[0][mt], 0, 0, 0);
            o[1][mt] = __builtin_amdgcn_mfma_f32_16x16x32_f16(vf, pb1, o[1][mt], 0, 0, 0);
          }
        }
      }

      __builtin_amdgcn_sched_barrier(0);
      if (kt + 2 < nkt) asm volatile("s_waitcnt vmcnt(2)" ::: "memory");
      else              asm volatile("s_waitcnt vmcnt(0)" ::: "memory");
      __builtin_amdgcn_s_barrier();
      __builtin_amdgcn_sched_barrier(0);
      const int tmp = b0; b0 = b1; b1 = b2; b2 = tmp;
    }

    // epilogue
    #pragma unroll
    for (int h = 0; h < 2; ++h) {
      const float inv = 1.0f / l[h];
      const int t = qrow0 + h * 16 + col;
      const size_t rowoff = ((size_t)b * T_ + t) * C_ + (size_t)hd * D_;
      #pragma unroll
      for (int mt = 0; mt < 4; ++mt) {
        f16x4 ov;
        #pragma unroll
        for (int r = 0; r < 4; ++r) ov[r] = (f16)(o[h][mt][r] * inv);
        *(f16x4*)&Aout[rowoff + mt * 16 + (g << 2)] = ov;
      }
    }
    __builtin_amdgcn_s_barrier();
  }
}

// ---------------- launch ----------------
extern "C" void kernel_launch(void* const* d_in, const int* in_sizes, int n_in,
                              void* d_out, int out_size, void* d_ws, size_t ws_size,
                              hipStream_t stream) {
  const float* x    = (const float*)d_in[0];
  const float* Wqkv = (const float*)d_in[1];
  const float* bqkv = (const float*)d_in[2];
  const float* Wout = (const float*)d_in[3];
  const float* bout = (const float*)d_in[4];
  float* out = (float*)d_out;

  char* ws = (char*)d_ws;
  f16* xb     = (f16*)ws;                   // 16MB (x in f16; later reused as Aout)
  f16* Wqkv_t = (f16*)(ws + (16u << 20));   // 6MB  [3072,1024]
  f16* Wout_t = (f16*)(ws + (22u << 20));   // 2MB  [1024,1024]
  f16* Qb     = (f16*)(ws + (24u << 20));   // 16MB [B,H,T,D]
  f16* Kb     = (f16*)(ws + (40u << 20));   // 16MB [B,H,T,D]
  f16* Vtb    = (f16*)(ws + (56u << 20));   // 16MB [B,H,D,T]

  cvt_kernel<<<2048, 256, 0, stream>>>(x, xb, (B_ * T_ * C_) / 4);
  dim3 g1(3072 / 32, 1024 / 32);
  transpose_cvt_kernel<<<g1, 256, 0, stream>>>(Wqkv, Wqkv_t, 1024, 3072);
  dim3 g2(1024 / 32, 1024 / 32);
  transpose_cvt_kernel<<<g2, 256, 0, stream>>>(Wout, Wout_t, 1024, 1024);

  gemm_kernel<0><<<64 * 24, 256, 0, stream>>>(xb, Wqkv_t, bqkv, nullptr,
                                              Qb, Kb, Vtb, 8192, 3072, 1024);
  attn_kernel<<<256, 512, 0, stream>>>(Qb, Kb, Vtb, xb /*Aout alias*/);
  gemm_kernel<1><<<64 * 8, 256, 0, stream>>>(xb, Wout_t, bout, out,
                                             nullptr, nullptr, nullptr, 8192, 1024, 1024);
}

// Round 7
// 210.751 us; speedup vs baseline: 1.0875x; 1.0109x over previous
//
#include <hip/hip_runtime.h>

typedef _Float16 f16;
typedef _Float16 f16x4 __attribute__((ext_vector_type(4)));
typedef _Float16 f16x8 __attribute__((ext_vector_type(8)));
typedef float    f32x4 __attribute__((ext_vector_type(4)));

#define B_ 4
#define T_ 2048
#define C_ 1024
#define H_ 16
#define D_ 64

__device__ __forceinline__ void gload_lds16(const f16* g, f16* l) {
  __builtin_amdgcn_global_load_lds(
      (const __attribute__((address_space(1))) unsigned int*)g,
      (__attribute__((address_space(3))) unsigned int*)l, 16, 0, 0);
}

// ---------------- prep kernels ----------------
__global__ void cvt_kernel(const float* __restrict__ in, f16* __restrict__ out, int n4) {
  int i = blockIdx.x * blockDim.x + threadIdx.x;
  int stride = gridDim.x * blockDim.x;
  for (; i < n4; i += stride) {
    float4 v = ((const float4*)in)[i];
    f16x4 h = { (f16)v.x, (f16)v.y, (f16)v.z, (f16)v.w };
    ((f16x4*)out)[i] = h;
  }
}

__global__ void transpose_cvt_kernel(const float* __restrict__ W, f16* __restrict__ Wt,
                                     int K, int N) {
  __shared__ f16 tile[32][33];
  int bx = blockIdx.x, by = blockIdx.y;
  int tx = threadIdx.x & 31, ty = threadIdx.x >> 5;
  #pragma unroll
  for (int i = ty; i < 32; i += 8)
    tile[i][tx] = (f16)W[(size_t)(by * 32 + i) * N + bx * 32 + tx];
  __syncthreads();
  #pragma unroll
  for (int i = ty; i < 32; i += 8)
    Wt[(size_t)(bx * 32 + i) * K + by * 32 + tx] = tile[tx][i];
}

// ============ 256x256 8-phase QKV GEMM, CORRECTED (row&7)<<4 swizzle ============
// A[8192,1024] * Bt[3072,1024]^T + bias -> scatter Q/K/Vt. 8 waves (2Mx4N),
// per-wave 128x64, BK=64, dbuf x 2-half LDS (128KB). Banks: 128B rows alias
// (bank = cb/4), so read swizzle must spread each 16-row group across quads:
// phys_cb = cb ^ ((row&7)<<4). Staged linearly with pre-swizzled global src.
__global__ __launch_bounds__(512, 2)
void gemm256_kernel(const f16* __restrict__ A, const f16* __restrict__ Bt,
                    const float* __restrict__ bias,
                    f16* __restrict__ q, f16* __restrict__ kk, f16* __restrict__ vt) {
  const int K_ = 1024;
  __shared__ __align__(16) f16 As[2][2][128 * 64];
  __shared__ __align__(16) f16 Bs[2][2][128 * 64];

  const int bid = blockIdx.x;
  const int wg = (bid & 7) * 48 + (bid >> 3);   // bijective XCD swizzle (384%8==0)
  const int bm = wg / 12, bn = wg % 12;
  const int m0 = bm << 8, n0 = bn << 8;
  const int lane = threadIdx.x & 63, wid = threadIdx.x >> 6;
  const int wm = wid >> 2;            // A half
  const int bhalf = (wid >> 1) & 1;   // B half
  const int brow0 = (wid & 1) << 6;
  const int rr = lane & 15, g = lane >> 4;

  f32x4 acc[8][4] = {};

  // staging: lane l -> dest row = c*64 + wid*8 + (l>>3), slot l&7.
  // logical slot at phys = slot ^ (row&7) = (l&7) ^ ((l>>3)&7)
  const int srow = (wid << 3) + (lane >> 3);
  const int scol = (((lane & 7) ^ ((lane >> 3) & 7)) << 3);  // f16 units
  const f16* Abase = A + (size_t)(m0 + srow) * K_ + scol;
  const f16* Bbase = Bt + (size_t)(n0 + srow) * K_ + scol;

  auto STAGE_A = [&](int buf, int half, int tile) {
    #pragma unroll
    for (int c = 0; c < 2; ++c)
      gload_lds16(Abase + (size_t)(half * 128 + c * 64) * K_ + tile * 64,
                  &As[buf][half][c * 4096 + wid * 512]);
  };
  auto STAGE_B = [&](int buf, int half, int tile) {
    #pragma unroll
    for (int c = 0; c < 2; ++c)
      gload_lds16(Bbase + (size_t)(half * 128 + c * 64) * K_ + tile * 64,
                  &Bs[buf][half][c * 4096 + wid * 512]);
  };

  auto LDA = [&](int buf, int mhalf, int kkk, f16x8* af) {
    #pragma unroll
    for (int f = 0; f < 4; ++f)
      af[f] = *(const f16x8*)((const char*)&As[buf][wm][0]
               + (mhalf * 64 + f * 16 + rr) * 128
               + ((kkk * 64 + g * 16) ^ ((rr & 7) << 4)));
  };
  auto LDB = [&](int buf, int kkk, f16x8* bf) {
    #pragma unroll
    for (int nf = 0; nf < 4; ++nf)
      bf[nf] = *(const f16x8*)((const char*)&Bs[buf][bhalf][0]
               + (brow0 + nf * 16 + rr) * 128
               + ((kkk * 64 + g * 16) ^ ((rr & 7) << 4)));
  };

  #define BAR() { __builtin_amdgcn_s_barrier(); __builtin_amdgcn_sched_barrier(0); }
  #define MMA(MH, AF, BF) { \
    __builtin_amdgcn_s_setprio(1); \
    _Pragma("unroll") \
    for (int f = 0; f < 4; ++f) \
      _Pragma("unroll") \
      for (int nf = 0; nf < 4; ++nf) \
        acc[(MH) * 4 + f][nf] = \
            __builtin_amdgcn_mfma_f32_16x16x32_f16(AF[f], BF[nf], acc[(MH) * 4 + f][nf], 0, 0, 0); \
    __builtin_amdgcn_s_setprio(0); }

  STAGE_A(0, 0, 0); STAGE_A(0, 1, 0);
  STAGE_B(0, 0, 0); STAGE_B(0, 1, 0);
  STAGE_B(1, 0, 1);
  asm volatile("s_waitcnt vmcnt(2)" ::: "memory");
  BAR();

  const int NT = 16;
  #pragma unroll 1
  for (int i = 0; i < 8; ++i) {
    const int t1 = 2 * i + 1, t2 = 2 * i + 2, t3 = 2 * i + 3;
    f16x8 af[4], bf[4];
    // ph1
    LDB(0, 0, bf); LDA(0, 0, 0, af);
    STAGE_B(1, 1, t1);
    BAR(); MMA(0, af, bf); BAR();
    // ph2
    LDA(0, 1, 0, af);
    STAGE_A(1, 0, t1);
    BAR(); MMA(1, af, bf); BAR();
    // ph3
    LDB(0, 1, bf); LDA(0, 0, 1, af);
    STAGE_A(1, 1, t1);
    BAR(); MMA(0, af, bf); BAR();
    // ph4 (GATE)
    LDA(0, 1, 1, af);
    if (t2 < NT) {
      STAGE_B(0, 0, t2);
      asm volatile("s_waitcnt vmcnt(2)" ::: "memory");
    } else {
      asm volatile("s_waitcnt vmcnt(0)" ::: "memory");
    }
    BAR(); MMA(1, af, bf); BAR();
    // ph5
    LDB(1, 0, bf); LDA(1, 0, 0, af);
    if (t2 < NT) STAGE_B(0, 1, t2);
    BAR(); MMA(0, af, bf); BAR();
    // ph6
    LDA(1, 1, 0, af);
    if (t2 < NT) STAGE_A(0, 0, t2);
    BAR(); MMA(1, af, bf); BAR();
    // ph7
    LDB(1, 1, bf); LDA(1, 0, 1, af);
    if (t2 < NT) STAGE_A(0, 1, t2);
    BAR(); MMA(0, af, bf); BAR();
    // ph8 (GATE)
    LDA(1, 1, 1, af);
    if (t3 < NT) {
      STAGE_B(1, 0, t3);
      asm volatile("s_waitcnt vmcnt(2)" ::: "memory");
    } else if (i < 7) {
      asm volatile("s_waitcnt vmcnt(0)" ::: "memory");
    }
    BAR(); MMA(1, af, bf); BAR();
  }
  #undef MMA
  #undef BAR

  const int col = lane & 15;
  const int row4 = (lane >> 4) << 2;
  const int seg = n0 >> 10;
  #pragma unroll
  for (int mi = 0; mi < 8; ++mi) {
    #pragma unroll
    for (int nf = 0; nf < 4; ++nf) {
      const int n = n0 + (wid & 3) * 64 + nf * 16 + col;
      const float bn_ = bias[n];
      const int cc = n & 1023;
      const int h = cc >> 6, d = cc & 63;
      #pragma unroll
      for (int r = 0; r < 4; ++r) {
        const int m = m0 + wm * 128 + mi * 16 + row4 + r;
        const float v = acc[mi][nf][r] + bn_;
        const int b = m >> 11, t = m & 2047;
        const size_t bh = (size_t)b * 16 + h;
        const f16 hv = (f16)v;
        if (seg == 0)      q [(bh * T_ + t) * D_ + d] = hv;
        else if (seg == 1) kk[(bh * T_ + t) * D_ + d] = hv;
        else               vt[(bh * D_ + d) * T_ + t] = hv;
      }
    }
  }
}

// ---------------- 128^2 GEMM (out-proj, unchanged) ----------------
__global__ __launch_bounds__(256, 3)
void gemm_kernel(const f16* __restrict__ A, const f16* __restrict__ Bt,
                 const float* __restrict__ bias, float* __restrict__ outF,
                 int M, int N, int K) {
  __shared__ __align__(16) f16 As[3][128 * 32];
  __shared__ __align__(16) f16 Bs[3][128 * 32];
  const int nbn = N >> 7;
  const int bid = blockIdx.x;
  const int bm = bid / nbn, bn = bid % nbn;
  const int m0 = bm << 7, n0 = bn << 7;
  const int tid = threadIdx.x;
  const int lane = tid & 63, wid = tid >> 6;
  const int wr = wid >> 1, wc = wid & 1;

  f32x4 acc[4][4] = {};

  const int srow = lane >> 2;
  const int scol = (((lane & 3) ^ ((lane >> 2) & 3)) << 3);
  const f16* Abase = A + (size_t)(m0 + srow) * K + scol;
  const f16* Bbase = Bt + (size_t)(n0 + srow) * K + scol;

  auto stage = [&](int buf, int kt) {
    const int c0 = wid * 2;
    #pragma unroll
    for (int c = c0; c < c0 + 2; ++c) {
      gload_lds16(Abase + (size_t)c * 16 * K + kt * 32, &As[buf][c * 512]);
      gload_lds16(Bbase + (size_t)c * 16 * K + kt * 32, &Bs[buf][c * 512]);
    }
  };

  const int g = lane >> 4;
  const int rr = lane & 15;
  const int swz = (g ^ (rr & 3)) << 4;

  auto compute = [&](int buf) {
    f16x8 af[4], bf[4];
    #pragma unroll
    for (int t = 0; t < 4; ++t) {
      af[t] = *(const f16x8*)((const char*)&As[buf][0] + (wr * 64 + t * 16 + rr) * 64 + swz);
      bf[t] = *(const f16x8*)((const char*)&Bs[buf][0] + (wc * 64 + t * 16 + rr) * 64 + swz);
    }
    __builtin_amdgcn_s_setprio(1);
    #pragma unroll
    for (int i = 0; i < 4; ++i)
      #pragma unroll
      for (int j = 0; j < 4; ++j)
        acc[i][j] = __builtin_amdgcn_mfma_f32_16x16x32_f16(af[i], bf[j], acc[i][j], 0, 0, 0);
    __builtin_amdgcn_s_setprio(0);
  };

  const int nk = K >> 5;
  int bcur = 0, bnext = 1, bnn = 2;
  stage(0, 0);
  stage(1, 1);
  asm volatile("s_waitcnt vmcnt(4)" ::: "memory");
  __builtin_amdgcn_s_barrier();
  __builtin_amdgcn_sched_barrier(0);
  for (int t = 0; t < nk; ++t) {
    if (t + 2 < nk) stage(bnn, t + 2);
    compute(bcur);
    if (t + 1 < nk) {
      if (t + 2 < nk) asm volatile("s_waitcnt vmcnt(4)" ::: "memory");
      else            asm volatile("s_waitcnt vmcnt(0)" ::: "memory");
      __builtin_amdgcn_s_barrier();
      __builtin_amdgcn_sched_barrier(0);
    }
    const int tmp = bcur; bcur = bnext; bnext = bnn; bnn = tmp;
  }

  const int col = lane & 15;
  const int row4 = (lane >> 4) << 2;
  #pragma unroll
  for (int i = 0; i < 4; ++i) {
    #pragma unroll
    for (int j = 0; j < 4; ++j) {
      const int n = n0 + wc * 64 + j * 16 + col;
      const float bn_ = bias[n];
      #pragma unroll
      for (int r = 0; r < 4; ++r) {
        const int m = m0 + wr * 64 + i * 16 + row4 + r;
        outF[(size_t)m * N + n] = acc[i][j][r] + bn_;
      }
    }
  }
}

// ---------------- causal flash attention: 512 blocks x 4 waves, 2 blocks/CU ----
// wgid = (bid&7)*64 + bid>>3; bh = wgid>>3 (8 bh/XCD), pr = wgid&7.
// Block does 128-row q-tiles (pr, 15-pr) -> uniform 34 kt. Wave owns 32 q-rows.
// LDS 64KB: K/V triple-buffered (swizzled), Pt XOR layout (no pad).
__global__ __launch_bounds__(256, 2)
void attn_kernel(const f16* __restrict__ Q, const f16* __restrict__ Kg,
                 const f16* __restrict__ Vt, f16* __restrict__ Aout) {
  __shared__ __align__(16) f16 Ks[3][64 * 64];   // [kvrow][d], 128B rows, swizzled
  __shared__ __align__(16) f16 Vs[3][64 * 64];   // [d][kv],   128B rows, swizzled
  __shared__ __align__(16) f16 Pt[4][32 * 64];   // per-wave P^T, XOR layout

  const int bid = blockIdx.x;
  const int wgid = (bid & 7) * 64 + (bid >> 3);
  const int bh = wgid >> 3;
  const int pr = wgid & 7;
  const int lane = threadIdx.x & 63, w = threadIdx.x >> 6;
  const int col = lane & 15;
  const int g = lane >> 4;
  const int ko = g << 3;

  const f16* Qp = Q + (size_t)bh * T_ * D_;
  const f16* Kp = Kg + (size_t)bh * T_ * D_;
  const f16* Vp = Vt + (size_t)bh * D_ * T_;

  const int sr = lane >> 3;                        // row within 8-row chunk
  const int sc = ((lane & 7) ^ (sr & 7)) << 3;     // pre-swizzled src col (f16)

  auto stage = [&](int buf, int kb) {
    #pragma unroll
    for (int c2 = 0; c2 < 2; ++c2) {
      const int c = (w << 1) + c2;                 // wave stages chunks 2w,2w+1
      gload_lds16(Kp + (size_t)(kb + (c << 3) + sr) * D_ + sc, &Ks[buf][c * 512]);
      gload_lds16(Vp + (size_t)((c << 3) + sr) * T_ + kb + sc, &Vs[buf][c * 512]);
    }
  };
  auto ldsK = [&](int buf, int krow, int d0) -> f16x8 {
    const int off = krow * 128 + ((d0 << 1) ^ ((krow & 7) << 4));
    return *(const f16x8*)((const char*)&Ks[buf][0] + off);
  };
  auto ldsV = [&](int buf, int drow, int k0) -> f16x8 {
    const int off = drow * 128 + ((k0 << 1) ^ ((drow & 7) << 4));
    return *(const f16x8*)((const char*)&Vs[buf][0] + off);
  };

  char* PtW = (char*)&Pt[w][0];
  const int b = bh >> 4, hd = bh & 15;

  #pragma unroll 1
  for (int tt = 0; tt < 2; ++tt) {
    const int ti = tt ? (15 - pr) : pr;
    const int qrow0 = (ti << 7) + (w << 5);
    const int nkt = (ti << 1) + 2;

    f16x8 qf[2][2];
    #pragma unroll
    for (int h = 0; h < 2; ++h)
      #pragma unroll
      for (int s = 0; s < 2; ++s) {
        f16x8 t = *(const f16x8*)&Qp[(size_t)(qrow0 + h * 16 + col) * D_ + s * 32 + ko];
        #pragma unroll
        for (int e = 0; e < 8; ++e) t[e] = t[e] * (f16)0.125f;
        qf[h][s] = t;
      }

    f32x4 o[2][4] = {};
    float m[2] = {-1e30f, -1e30f}, l[2] = {0.f, 0.f};

    int b0 = 0, b1 = 1, b2 = 2;
    stage(b0, 0);
    stage(b1, 64);
    asm volatile("s_waitcnt vmcnt(4)" ::: "memory");
    __builtin_amdgcn_s_barrier();
    __builtin_amdgcn_sched_barrier(0);

    for (int kt = 0; kt < nkt; ++kt) {
      const int kb = kt << 6;
      if (kt + 2 < nkt) stage(b2, kb + 128);

      if (kb <= qrow0 + 31) {
        f32x4 sc2[2][4] = {};
        #pragma unroll
        for (int s = 0; s < 2; ++s)
          #pragma unroll
          for (int mt = 0; mt < 4; ++mt) {
            f16x8 kf = ldsK(b0, mt * 16 + col, s * 32 + ko);
            sc2[0][mt] = __builtin_amdgcn_mfma_f32_16x16x32_f16(kf, qf[0][s], sc2[0][mt], 0, 0, 0);
            sc2[1][mt] = __builtin_amdgcn_mfma_f32_16x16x32_f16(kf, qf[1][s], sc2[1][mt], 0, 0, 0);
          }

        if (kb + 63 > qrow0) {
          #pragma unroll
          for (int mt = 0; mt < 4; ++mt)
            #pragma unroll
            for (int r = 0; r < 4; ++r) {
              const int kv = kb + mt * 16 + (g << 2) + r;
              if (kv > qrow0 + col)      sc2[0][mt][r] = -1e30f;
              if (kv > qrow0 + 16 + col) sc2[1][mt][r] = -1e30f;
            }
        }

        float mx[2];
        #pragma unroll
        for (int h = 0; h < 2; ++h) {
          float v = fmaxf(fmaxf(fmaxf(sc2[h][0][0], sc2[h][0][1]), fmaxf(sc2[h][0][2], sc2[h][0][3])),
                          fmaxf(fmaxf(sc2[h][1][0], sc2[h][1][1]), fmaxf(sc2[h][1][2], sc2[h][1][3])));
          v = fmaxf(v, fmaxf(fmaxf(fmaxf(sc2[h][2][0], sc2[h][2][1]), fmaxf(sc2[h][2][2], sc2[h][2][3])),
                             fmaxf(fmaxf(sc2[h][3][0], sc2[h][3][1]), fmaxf(sc2[h][3][2], sc2[h][3][3]))));
          v = fmaxf(v, __shfl_xor(v, 16, 64));
          v = fmaxf(v, __shfl_xor(v, 32, 64));
          mx[h] = v;
        }

        if (!__all(fmaxf(mx[0] - m[0], mx[1] - m[1]) <= 8.f)) {
          #pragma unroll
          for (int h = 0; h < 2; ++h) {
            const float mnew = fmaxf(m[h], mx[h]);
            const float alpha = __expf(m[h] - mnew);
            m[h] = mnew;
            l[h] *= alpha;
            #pragma unroll
            for (int mt = 0; mt < 4; ++mt)
              #pragma unroll
              for (int r = 0; r < 4; ++r) o[h][mt][r] *= alpha;
          }
        }

        #pragma unroll
        for (int h = 0; h < 2; ++h) {
          float rs = 0.f;
          #pragma unroll
          for (int mt = 0; mt < 4; ++mt) {
            f16x4 ph;
            #pragma unroll
            for (int r = 0; r < 4; ++r) {
              const float p = __expf(sc2[h][mt][r] - m[h]);
              rs += p;
              ph[r] = (f16)p;
            }
            *(f16x4*)(PtW + (h * 16 + col) * 128 + (((mt << 5) + (g << 3)) ^ ((col & 7) << 4))) = ph;
          }
          rs += __shfl_xor(rs, 16, 64);
          rs += __shfl_xor(rs, 32, 64);
          l[h] += rs;
        }

        #pragma unroll
        for (int s = 0; s < 2; ++s) {
          const int pcb = ((s << 6) + (g << 4)) ^ ((col & 7) << 4);
          f16x8 pb0 = *(const f16x8*)(PtW + col * 128 + pcb);
          f16x8 pb1 = *(const f16x8*)(PtW + (16 + col) * 128 + pcb);
          #pragma unroll
          for (int mt = 0; mt < 4; ++mt) {
            f16x8 vf = ldsV(b0, mt * 16 + col, s * 32 + ko);
            o[0][mt] = __builtin_amdgcn_mfma_f32_16x16x32_f16(vf, pb0, o[0][mt], 0, 0, 0);
            o[1][mt] = __builtin_amdgcn_mfma_f32_16x16x32_f16(vf, pb1, o[1][mt], 0, 0, 0);
          }
        }
      }

      __builtin_amdgcn_sched_barrier(0);
      if (kt + 2 < nkt) asm volatile("s_waitcnt vmcnt(4)" ::: "memory");
      else              asm volatile("s_waitcnt vmcnt(0)" ::: "memory");
      __builtin_amdgcn_s_barrier();
      __builtin_amdgcn_sched_barrier(0);
      const int tmp = b0; b0 = b1; b1 = b2; b2 = tmp;
    }

    #pragma unroll
    for (int h = 0; h < 2; ++h) {
      const float inv = 1.0f / l[h];
      const int t = qrow0 + h * 16 + col;
      const size_t rowoff = ((size_t)b * T_ + t) * C_ + (size_t)hd * D_;
      #pragma unroll
      for (int mt = 0; mt < 4; ++mt) {
        f16x4 ov;
        #pragma unroll
        for (int r = 0; r < 4; ++r) ov[r] = (f16)(o[h][mt][r] * inv);
        *(f16x4*)&Aout[rowoff + mt * 16 + (g << 2)] = ov;
      }
    }
    __builtin_amdgcn_s_barrier();
  }
}

// ---------------- launch ----------------
extern "C" void kernel_launch(void* const* d_in, const int* in_sizes, int n_in,
                              void* d_out, int out_size, void* d_ws, size_t ws_size,
                              hipStream_t stream) {
  const float* x    = (const float*)d_in[0];
  const float* Wqkv = (const float*)d_in[1];
  const float* bqkv = (const float*)d_in[2];
  const float* Wout = (const float*)d_in[3];
  const float* bout = (const float*)d_in[4];
  float* out = (float*)d_out;

  char* ws = (char*)d_ws;
  f16* xb     = (f16*)ws;                   // 16MB (x in f16; later reused as Aout)
  f16* Wqkv_t = (f16*)(ws + (16u << 20));   // 6MB  [3072,1024]
  f16* Wout_t = (f16*)(ws + (22u << 20));   // 2MB  [1024,1024]
  f16* Qb     = (f16*)(ws + (24u << 20));   // 16MB [B,H,T,D]
  f16* Kb     = (f16*)(ws + (40u << 20));   // 16MB [B,H,T,D]
  f16* Vtb    = (f16*)(ws + (56u << 20));   // 16MB [B,H,D,T]

  cvt_kernel<<<2048, 256, 0, stream>>>(x, xb, (B_ * T_ * C_) / 4);
  dim3 g1(3072 / 32, 1024 / 32);
  transpose_cvt_kernel<<<g1, 256, 0, stream>>>(Wqkv, Wqkv_t, 1024, 3072);
  dim3 g2(1024 / 32, 1024 / 32);
  transpose_cvt_kernel<<<g2, 256, 0, stream>>>(Wout, Wout_t, 1024, 1024);

  gemm256_kernel<<<384, 512, 0, stream>>>(xb, Wqkv_t, bqkv, Qb, Kb, Vtb);
  attn_kernel<<<512, 256, 0, stream>>>(Qb, Kb, Vtb, xb /*Aout alias*/);
  gemm_kernel<<<64 * 8, 256, 0, stream>>>(xb, Wout_t, bout, out, 8192, 1024, 1024);
}

// Round 8
// 207.875 us; speedup vs baseline: 1.1025x; 1.0138x over previous
//
#include <hip/hip_runtime.h>

typedef _Float16 f16;
typedef _Float16 f16x4 __attribute__((ext_vector_type(4)));
typedef _Float16 f16x8 __attribute__((ext_vector_type(8)));
typedef float    f32x4 __attribute__((ext_vector_type(4)));

#define B_ 4
#define T_ 2048
#define C_ 1024
#define H_ 16
#define D_ 64

__device__ __forceinline__ void gload_lds16(const f16* g, f16* l) {
  __builtin_amdgcn_global_load_lds(
      (const __attribute__((address_space(1))) unsigned int*)g,
      (__attribute__((address_space(3))) unsigned int*)l, 16, 0, 0);
}

// ---------------- prep kernels ----------------
__global__ void cvt_kernel(const float* __restrict__ in, f16* __restrict__ out, int n4) {
  int i = blockIdx.x * blockDim.x + threadIdx.x;
  int stride = gridDim.x * blockDim.x;
  for (; i < n4; i += stride) {
    float4 v = ((const float4*)in)[i];
    f16x4 h = { (f16)v.x, (f16)v.y, (f16)v.z, (f16)v.w };
    ((f16x4*)out)[i] = h;
  }
}

__global__ void transpose_cvt_kernel(const float* __restrict__ W, f16* __restrict__ Wt,
                                     int K, int N) {
  __shared__ f16 tile[32][33];
  int bx = blockIdx.x, by = blockIdx.y;
  int tx = threadIdx.x & 31, ty = threadIdx.x >> 5;
  #pragma unroll
  for (int i = ty; i < 32; i += 8)
    tile[i][tx] = (f16)W[(size_t)(by * 32 + i) * N + bx * 32 + tx];
  __syncthreads();
  #pragma unroll
  for (int i = ty; i < 32; i += 8)
    Wt[(size_t)(bx * 32 + i) * K + by * 32 + tx] = tile[tx][i];
}

// ---------------- 128^2 GEMM (R6 version, measured 98.4us): A*Bt^T + bias ----
template <int EPI>
__global__ __launch_bounds__(256, 3)
void gemm_kernel(const f16* __restrict__ A, const f16* __restrict__ Bt,
                 const float* __restrict__ bias, float* __restrict__ outF,
                 f16* __restrict__ q, f16* __restrict__ kk, f16* __restrict__ vt,
                 int M, int N, int K) {
  __shared__ __align__(16) f16 As[3][128 * 32];
  __shared__ __align__(16) f16 Bs[3][128 * 32];
  const int nbn = N >> 7;
  const int bid = blockIdx.x;
  const int bm = bid / nbn, bn = bid % nbn;
  const int m0 = bm << 7, n0 = bn << 7;
  const int tid = threadIdx.x;
  const int lane = tid & 63, wid = tid >> 6;
  const int wr = wid >> 1, wc = wid & 1;

  f32x4 acc[4][4] = {};

  const int srow = lane >> 2;
  const int scol = (((lane & 3) ^ ((lane >> 2) & 3)) << 3);
  const f16* Abase = A + (size_t)(m0 + srow) * K + scol;
  const f16* Bbase = Bt + (size_t)(n0 + srow) * K + scol;

  auto stage = [&](int buf, int kt) {
    const int c0 = wid * 2;
    #pragma unroll
    for (int c = c0; c < c0 + 2; ++c) {
      gload_lds16(Abase + (size_t)c * 16 * K + kt * 32, &As[buf][c * 512]);
      gload_lds16(Bbase + (size_t)c * 16 * K + kt * 32, &Bs[buf][c * 512]);
    }
  };

  const int g = lane >> 4;
  const int rr = lane & 15;
  const int swz = (g ^ (rr & 3)) << 4;

  auto compute = [&](int buf) {
    f16x8 af[4], bf[4];
    #pragma unroll
    for (int t = 0; t < 4; ++t) {
      af[t] = *(const f16x8*)((const char*)&As[buf][0] + (wr * 64 + t * 16 + rr) * 64 + swz);
      bf[t] = *(const f16x8*)((const char*)&Bs[buf][0] + (wc * 64 + t * 16 + rr) * 64 + swz);
    }
    __builtin_amdgcn_s_setprio(1);
    #pragma unroll
    for (int i = 0; i < 4; ++i)
      #pragma unroll
      for (int j = 0; j < 4; ++j)
        acc[i][j] = __builtin_amdgcn_mfma_f32_16x16x32_f16(af[i], bf[j], acc[i][j], 0, 0, 0);
    __builtin_amdgcn_s_setprio(0);
  };

  const int nk = K >> 5;
  int bcur = 0, bnext = 1, bnn = 2;
  stage(0, 0);
  stage(1, 1);
  asm volatile("s_waitcnt vmcnt(4)" ::: "memory");
  __builtin_amdgcn_s_barrier();
  __builtin_amdgcn_sched_barrier(0);
  for (int t = 0; t < nk; ++t) {
    if (t + 2 < nk) stage(bnn, t + 2);
    compute(bcur);
    if (t + 1 < nk) {
      if (t + 2 < nk) asm volatile("s_waitcnt vmcnt(4)" ::: "memory");
      else            asm volatile("s_waitcnt vmcnt(0)" ::: "memory");
      __builtin_amdgcn_s_barrier();
      __builtin_amdgcn_sched_barrier(0);
    }
    const int tmp = bcur; bcur = bnext; bnext = bnn; bnn = tmp;
  }

  const int col = lane & 15;
  const int row4 = (lane >> 4) << 2;
  #pragma unroll
  for (int i = 0; i < 4; ++i) {
    #pragma unroll
    for (int j = 0; j < 4; ++j) {
      const int n = n0 + wc * 64 + j * 16 + col;
      const float bn_ = bias[n];
      #pragma unroll
      for (int r = 0; r < 4; ++r) {
        const int m = m0 + wr * 64 + i * 16 + row4 + r;
        const float v = acc[i][j][r] + bn_;
        if (EPI == 1) {
          outF[(size_t)m * N + n] = v;
        } else {
          const int which = n >> 10;           // 0=q 1=k 2=v
          const int cc = n & 1023;
          const int h = cc >> 6, d = cc & 63;
          const int b = m >> 11, t = m & 2047;
          const size_t bh = (size_t)b * 16 + h;
          const f16 hv = (f16)v;
          if (which == 0)      q [(bh * T_ + t) * D_ + d] = hv;
          else if (which == 1) kk[(bh * T_ + t) * D_ + d] = hv;
          else                 vt[(bh * D_ + d) * T_ + t] = hv;  // V transposed
        }
      }
    }
  }
}

// ---------------- causal flash attention: 4-slot ring, 2 kv-tiles/iter ----------
// 512 blocks (2/CU): wgid = (bid&7)*64 + bid>>3; bh = wgid>>3, pr = wgid&7.
// Block does 128-row q-tiles (pr, 15-pr) -> uniform 34 kt. 4 waves x 32 q-rows.
// One s_barrier + one vmcnt(0) per 2 kv-tiles; stages issued at iter top,
// drained at iter bottom (in-flight across full 2-tile compute).
__global__ __launch_bounds__(256, 2)
void attn_kernel(const f16* __restrict__ Q, const f16* __restrict__ Kg,
                 const f16* __restrict__ Vt, f16* __restrict__ Aout) {
  __shared__ __align__(16) f16 Ks[4][64 * 64];   // ring [kvrow][d], 128B rows, swizzled
  __shared__ __align__(16) f16 Vs[4][64 * 64];   // ring [d][kv],   128B rows, swizzled
  __shared__ __align__(16) f16 Pt[4][32 * 64];   // per-wave P^T, XOR layout

  const int bid = blockIdx.x;
  const int wgid = (bid & 7) * 64 + (bid >> 3);
  const int bh = wgid >> 3;
  const int pr = wgid & 7;
  const int lane = threadIdx.x & 63, w = threadIdx.x >> 6;
  const int col = lane & 15;
  const int g = lane >> 4;
  const int ko = g << 3;

  const f16* Qp = Q + (size_t)bh * T_ * D_;
  const f16* Kp = Kg + (size_t)bh * T_ * D_;
  const f16* Vp = Vt + (size_t)bh * D_ * T_;

  const int sr = lane >> 3;
  const int sc = ((lane & 7) ^ (sr & 7)) << 3;

  auto stage = [&](int buf, int kb) {
    #pragma unroll
    for (int c2 = 0; c2 < 2; ++c2) {
      const int c = (w << 1) + c2;
      gload_lds16(Kp + (size_t)(kb + (c << 3) + sr) * D_ + sc, &Ks[buf][c * 512]);
      gload_lds16(Vp + (size_t)((c << 3) + sr) * T_ + kb + sc, &Vs[buf][c * 512]);
    }
  };
  auto ldsK = [&](int buf, int krow, int d0) -> f16x8 {
    const int off = krow * 128 + ((d0 << 1) ^ ((krow & 7) << 4));
    return *(const f16x8*)((const char*)&Ks[buf][0] + off);
  };
  auto ldsV = [&](int buf, int drow, int k0) -> f16x8 {
    const int off = drow * 128 + ((k0 << 1) ^ ((drow & 7) << 4));
    return *(const f16x8*)((const char*)&Vs[buf][0] + off);
  };

  char* PtW = (char*)&Pt[w][0];
  const int b = bh >> 4, hd = bh & 15;

  #pragma unroll 1
  for (int tt = 0; tt < 2; ++tt) {
    const int ti = tt ? (15 - pr) : pr;
    const int qrow0 = (ti << 7) + (w << 5);
    const int np = ti + 1;                      // iterations; 2 kv-tiles each

    f16x8 qf[2][2];
    #pragma unroll
    for (int h = 0; h < 2; ++h)
      #pragma unroll
      for (int s = 0; s < 2; ++s) {
        f16x8 t = *(const f16x8*)&Qp[(size_t)(qrow0 + h * 16 + col) * D_ + s * 32 + ko];
        #pragma unroll
        for (int e = 0; e < 8; ++e) t[e] = t[e] * (f16)0.125f;
        qf[h][s] = t;
      }

    f32x4 o[2][4] = {};
    float m[2] = {-1e30f, -1e30f}, l[2] = {0.f, 0.f};

    auto COMPUTE = [&](int buf, int kb) {
      f32x4 sc2[2][4] = {};
      #pragma unroll
      for (int s = 0; s < 2; ++s)
        #pragma unroll
        for (int mt = 0; mt < 4; ++mt) {
          f16x8 kf = ldsK(buf, mt * 16 + col, s * 32 + ko);
          sc2[0][mt] = __builtin_amdgcn_mfma_f32_16x16x32_f16(kf, qf[0][s], sc2[0][mt], 0, 0, 0);
          sc2[1][mt] = __builtin_amdgcn_mfma_f32_16x16x32_f16(kf, qf[1][s], sc2[1][mt], 0, 0, 0);
        }

      if (kb + 63 > qrow0) {
        #pragma unroll
        for (int mt = 0; mt < 4; ++mt)
          #pragma unroll
          for (int r = 0; r < 4; ++r) {
            const int kv = kb + mt * 16 + (g << 2) + r;
            if (kv > qrow0 + col)      sc2[0][mt][r] = -1e30f;
            if (kv > qrow0 + 16 + col) sc2[1][mt][r] = -1e30f;
          }
      }

      float mx[2];
      #pragma unroll
      for (int h = 0; h < 2; ++h) {
        float v = fmaxf(fmaxf(fmaxf(sc2[h][0][0], sc2[h][0][1]), fmaxf(sc2[h][0][2], sc2[h][0][3])),
                        fmaxf(fmaxf(sc2[h][1][0], sc2[h][1][1]), fmaxf(sc2[h][1][2], sc2[h][1][3])));
        v = fmaxf(v, fmaxf(fmaxf(fmaxf(sc2[h][2][0], sc2[h][2][1]), fmaxf(sc2[h][2][2], sc2[h][2][3])),
                           fmaxf(fmaxf(sc2[h][3][0], sc2[h][3][1]), fmaxf(sc2[h][3][2], sc2[h][3][3]))));
        v = fmaxf(v, __shfl_xor(v, 16, 64));
        v = fmaxf(v, __shfl_xor(v, 32, 64));
        mx[h] = v;
      }

      if (!__all(fmaxf(mx[0] - m[0], mx[1] - m[1]) <= 8.f)) {
        #pragma unroll
        for (int h = 0; h < 2; ++h) {
          const float mnew = fmaxf(m[h], mx[h]);
          const float alpha = __expf(m[h] - mnew);
          m[h] = mnew;
          l[h] *= alpha;
          #pragma unroll
          for (int mt = 0; mt < 4; ++mt)
            #pragma unroll
            for (int r = 0; r < 4; ++r) o[h][mt][r] *= alpha;
        }
      }

      #pragma unroll
      for (int h = 0; h < 2; ++h) {
        float rs = 0.f;
        #pragma unroll
        for (int mt = 0; mt < 4; ++mt) {
          f16x4 ph;
          #pragma unroll
          for (int r = 0; r < 4; ++r) {
            const float p = __expf(sc2[h][mt][r] - m[h]);
            rs += p;
            ph[r] = (f16)p;
          }
          *(f16x4*)(PtW + (h * 16 + col) * 128 + (((mt << 5) + (g << 3)) ^ ((col & 7) << 4))) = ph;
        }
        rs += __shfl_xor(rs, 16, 64);
        rs += __shfl_xor(rs, 32, 64);
        l[h] += rs;
      }

      #pragma unroll
      for (int s = 0; s < 2; ++s) {
        const int pcb = ((s << 6) + (g << 4)) ^ ((col & 7) << 4);
        f16x8 pb0 = *(const f16x8*)(PtW + col * 128 + pcb);
        f16x8 pb1 = *(const f16x8*)(PtW + (16 + col) * 128 + pcb);
        #pragma unroll
        for (int mt = 0; mt < 4; ++mt) {
          f16x8 vf = ldsV(buf, mt * 16 + col, s * 32 + ko);
          o[0][mt] = __builtin_amdgcn_mfma_f32_16x16x32_f16(vf, pb0, o[0][mt], 0, 0, 0);
          o[1][mt] = __builtin_amdgcn_mfma_f32_16x16x32_f16(vf, pb1, o[1][mt], 0, 0, 0);
        }
      }
    };

    // prologue: tiles 0,1 -> ring slots 0,1
    stage(0, 0);
    stage(1, 64);
    asm volatile("s_waitcnt vmcnt(0)" ::: "memory");
    __builtin_amdgcn_s_barrier();
    __builtin_amdgcn_sched_barrier(0);

    #pragma unroll 1
    for (int j = 0; j < np; ++j) {
      const int kb0 = j << 7;
      const int s0 = (j << 1) & 3, s1 = ((j << 1) + 1) & 3;
      if (j + 1 < np) {                 // prefetch tiles 2j+2, 2j+3
        stage((s0 + 2) & 3, kb0 + 128);
        stage((s1 + 2) & 3, kb0 + 192);
      }
      COMPUTE(s0, kb0);
      if (kb0 + 64 <= qrow0 + 31) COMPUTE(s1, kb0 + 64);

      __builtin_amdgcn_sched_barrier(0);
      asm volatile("s_waitcnt vmcnt(0)" ::: "memory");
      __builtin_amdgcn_s_barrier();
      __builtin_amdgcn_sched_barrier(0);
    }

    #pragma unroll
    for (int h = 0; h < 2; ++h) {
      const float inv = 1.0f / l[h];
      const int t = qrow0 + h * 16 + col;
      const size_t rowoff = ((size_t)b * T_ + t) * C_ + (size_t)hd * D_;
      #pragma unroll
      for (int mt = 0; mt < 4; ++mt) {
        f16x4 ov;
        #pragma unroll
        for (int r = 0; r < 4; ++r) ov[r] = (f16)(o[h][mt][r] * inv);
        *(f16x4*)&Aout[rowoff + mt * 16 + (g << 2)] = ov;
      }
    }
    __builtin_amdgcn_s_barrier();
  }
}

// ---------------- launch ----------------
extern "C" void kernel_launch(void* const* d_in, const int* in_sizes, int n_in,
                              void* d_out, int out_size, void* d_ws, size_t ws_size,
                              hipStream_t stream) {
  const float* x    = (const float*)d_in[0];
  const float* Wqkv = (const float*)d_in[1];
  const float* bqkv = (const float*)d_in[2];
  const float* Wout = (const float*)d_in[3];
  const float* bout = (const float*)d_in[4];
  float* out = (float*)d_out;

  char* ws = (char*)d_ws;
  f16* xb     = (f16*)ws;                   // 16MB (x in f16; later reused as Aout)
  f16* Wqkv_t = (f16*)(ws + (16u << 20));   // 6MB  [3072,1024]
  f16* Wout_t = (f16*)(ws + (22u << 20));   // 2MB  [1024,1024]
  f16* Qb     = (f16*)(ws + (24u << 20));   // 16MB [B,H,T,D]
  f16* Kb     = (f16*)(ws + (40u << 20));   // 16MB [B,H,T,D]
  f16* Vtb    = (f16*)(ws + (56u << 20));   // 16MB [B,H,D,T]

  cvt_kernel<<<2048, 256, 0, stream>>>(x, xb, (B_ * T_ * C_) / 4);
  dim3 g1(3072 / 32, 1024 / 32);
  transpose_cvt_kernel<<<g1, 256, 0, stream>>>(Wqkv, Wqkv_t, 1024, 3072);
  dim3 g2(1024 / 32, 1024 / 32);
  transpose_cvt_kernel<<<g2, 256, 0, stream>>>(Wout, Wout_t, 1024, 1024);

  gemm_kernel<0><<<64 * 24, 256, 0, stream>>>(xb, Wqkv_t, bqkv, nullptr,
                                              Qb, Kb, Vtb, 8192, 3072, 1024);
  attn_kernel<<<512, 256, 0, stream>>>(Qb, Kb, Vtb, xb /*Aout alias*/);
  gemm_kernel<1><<<64 * 8, 256, 0, stream>>>(xb, Wout_t, bout, out,
                                             nullptr, nullptr, nullptr, 8192, 1024, 1024);
}